// Round 13
// baseline (457.997 us; speedup 1.0000x reference)
//
#include <hip/hip_runtime.h>
#include <hip/hip_bf16.h>
#include <cstdint>
#include <cstddef>

typedef __bf16 bf16;
typedef __attribute__((ext_vector_type(8))) __bf16 bf16x8;
typedef __attribute__((ext_vector_type(4))) __bf16 bf16x4;
typedef __attribute__((ext_vector_type(4))) float f32x4;

#define BB 4
#define TT 4096
#define DD 512
#define MM (BB * TT)              // 16384 rows
#define OUT1_OFF ((size_t)MM * DD)

typedef __attribute__((address_space(1))) void as1_void;
typedef __attribute__((address_space(3))) void as3_void;

__device__ __forceinline__ void gl_lds16(const void* g, void* l) {
    __builtin_amdgcn_global_load_lds((as1_void*)(uintptr_t)g,
                                     (as3_void*)(uintptr_t)l, 16, 0, 0);
}

#define SIGM(x) (__builtin_amdgcn_rcpf(1.f + __expf(-(x))))

// ---------------------------------------------------------------- transpose
__global__ void transpose_bf16(const float* __restrict__ in, bf16* __restrict__ out,
                               int R, int C) {
    __shared__ float tile[32][33];
    const int c0 = blockIdx.x * 32, r0 = blockIdx.y * 32;
    const int tx = threadIdx.x, ty = threadIdx.y;
#pragma unroll
    for (int i = 0; i < 32; i += 8)
        tile[ty + i][tx] = in[(size_t)(r0 + ty + i) * C + (c0 + tx)];
    __syncthreads();
#pragma unroll
    for (int i = 0; i < 32; i += 8)
        out[(size_t)(c0 + ty + i) * R + (r0 + tx)] = (bf16)tile[tx][ty + i];
}

__global__ void pack_bias(const float* __restrict__ a, const float* __restrict__ b,
                          const float* __restrict__ c, const float* __restrict__ d,
                          float* __restrict__ o) {
    const int i = blockIdx.x * 256 + threadIdx.x;
    if (i < 2048) {
        const float* s = (i < 512) ? a : (i < 1024) ? b : (i < 1536) ? c : d;
        o[i] = s[i & 511];
    }
}

__global__ void zero_kernel(float* __restrict__ p, int n) {
    const int i = blockIdx.x * 256 + threadIdx.x;
    if (i < n) p[i] = 0.f;
}

// ---------------------------------------------------------------- layernorm
__global__ __launch_bounds__(256) void ln_kernel(
    const float* __restrict__ X, const float* __restrict__ Xadd,
    const float* __restrict__ gw, const float* __restrict__ bw,
    bf16* __restrict__ out) {
    const int row = blockIdx.x * 4 + (threadIdx.x >> 6);
    const int lane = threadIdx.x & 63;
    const float* xr = X + (size_t)row * DD + lane * 8;
    float v[8];
    float4 v0 = *(const float4*)xr;
    float4 v1 = *(const float4*)(xr + 4);
    v[0] = v0.x; v[1] = v0.y; v[2] = v0.z; v[3] = v0.w;
    v[4] = v1.x; v[5] = v1.y; v[6] = v1.z; v[7] = v1.w;
    if (Xadd) {
        const float* ad = Xadd + (size_t)row * DD + lane * 8;
        float4 a0 = *(const float4*)ad;
        float4 a1 = *(const float4*)(ad + 4);
        v[0] += a0.x; v[1] += a0.y; v[2] += a0.z; v[3] += a0.w;
        v[4] += a1.x; v[5] += a1.y; v[6] += a1.z; v[7] += a1.w;
    }
    float s = 0.f, ss = 0.f;
#pragma unroll
    for (int i = 0; i < 8; ++i) { s += v[i]; ss += v[i] * v[i]; }
#pragma unroll
    for (int o = 32; o; o >>= 1) { s += __shfl_down(s, o); ss += __shfl_down(ss, o); }
    s = __shfl(s, 0); ss = __shfl(ss, 0);
    const float mu = s * (1.f / DD);
    const float var = ss * (1.f / DD) - mu * mu;
    const float rstd = rsqrtf(var + 1e-5f);
    bf16x8 o8;
#pragma unroll
    for (int i = 0; i < 8; ++i)
        o8[i] = (bf16)((v[i] - mu) * rstd * gw[lane * 8 + i] + bw[lane * 8 + i]);
    *(bf16x8*)(out + (size_t)row * DD + lane * 8) = o8;
}

#define MF(a_, b_, c_) c_ = __builtin_amdgcn_mfma_f32_16x16x32_bf16(a_, b_, c_, 0, 0, 0)

// ---------------------------------------------------------------- GEMM: 1-wave 64x64 + swizzle
// R8 barrier-free structure + R10 both-sides XOR swizzle + tri-buffer.
// In this structure LDS-read conflicts are NOT hidden (no barriers; ~6-10
// independent waves/CU share the LDS pipe) -- the swizzle
// (phys_slot = log_slot ^ ((row>>1)&3)) removes the 8-way b128 conflict.
// Tri-buffer: STG(t+2) -> buf[(t-1)%3], whose reads retired before tile
// t-1's MFMAs (single-wave program order) => no lgkmcnt stall, no barriers.
// MODE 0: fused transform epilogue (lint4 {om,th,re,im} + pscalar partials)
// MODE 1: bf16 out = gelu(acc + bias)
template <int MODE>
__global__ __launch_bounds__(64) void gemm_wv(
    const bf16* __restrict__ A, const bf16* __restrict__ Bt,
    const float* __restrict__ bias, void* __restrict__ Cout,
    void* __restrict__ Cout2, int M, int N, int K) {
    __shared__ bf16 As[3][2048];
    __shared__ bf16 Bs[3][2048];
    const int lane = threadIdx.x;
    const int nb = N >> 6;
    const int nwg = gridDim.x;
    int bx = blockIdx.x;
    if ((nwg & 7) == 0) bx = (bx & 7) * (nwg >> 3) + (bx >> 3);  // XCD swizzle
    const int bm = bx / nb, bn = bx % nb;
    const int m0 = bm << 6, n0 = bn << 6;

    const int srow = lane >> 2;                                  // row in 16-row line
    const int scol = (((lane & 3) ^ ((lane >> 3) & 3)) << 3);    // pre-swizzled global col
    const bf16* Asrc = A + (size_t)(m0 + srow) * K + scol;
    const bf16* Bsrc = Bt + (size_t)(n0 + srow) * K + scol;
    const size_t rs16 = (size_t)16 * K;

    const int lr = lane & 15, lg = lane >> 4;
    const int sel = ((lg ^ ((lr >> 1) & 3)) << 3);               // swizzled 16B slot
    const int fbase = lr * 32 + sel;

#define STGW(buf, k0)                                          \
    do {                                                       \
        gl_lds16(Asrc + (k0),              &As[buf][0]);       \
        gl_lds16(Asrc + (k0) + rs16,       &As[buf][512]);     \
        gl_lds16(Asrc + (k0) + 2 * rs16,   &As[buf][1024]);    \
        gl_lds16(Asrc + (k0) + 3 * rs16,   &As[buf][1536]);    \
        gl_lds16(Bsrc + (k0),              &Bs[buf][0]);       \
        gl_lds16(Bsrc + (k0) + rs16,       &Bs[buf][512]);     \
        gl_lds16(Bsrc + (k0) + 2 * rs16,   &Bs[buf][1024]);    \
        gl_lds16(Bsrc + (k0) + 3 * rs16,   &Bs[buf][1536]);    \
    } while (0)

    f32x4 acc[4][4] = {};
    const int NT = K >> 5;
    STGW(0, 0);
    STGW(1, 32);
    int cur = 0;
    for (int t = 0; t < NT; ++t) {
        if (t + 1 < NT) asm volatile("s_waitcnt vmcnt(8)" ::: "memory");
        else            asm volatile("s_waitcnt vmcnt(0)" ::: "memory");
        const bf16* Ab = As[cur];
        const bf16* Bb = Bs[cur];
        bf16x8 af[4], bfv[4];
#pragma unroll
        for (int mi = 0; mi < 4; ++mi) af[mi] = *(const bf16x8*)&Ab[fbase + mi * 512];
#pragma unroll
        for (int ni = 0; ni < 4; ++ni) bfv[ni] = *(const bf16x8*)&Bb[fbase + ni * 512];
        if (t + 2 < NT) {
            const int stg = (cur == 0) ? 2 : cur - 1;
            STGW(stg, (t + 2) << 5);
        }
#pragma unroll
        for (int mi = 0; mi < 4; ++mi)
#pragma unroll
            for (int ni = 0; ni < 4; ++ni)
                acc[mi][ni] = __builtin_amdgcn_mfma_f32_16x16x32_bf16(
                    af[mi], bfv[ni], acc[mi][ni], 0, 0, 0);
        cur = (cur == 2) ? 0 : cur + 1;
    }
#undef STGW

    if constexpr (MODE == 0) {
        const int cls = n0 >> 9;                 // 0=p 1=theta 2=re 3=im
        if (cls == 0) {
            const int pidx = n0 >> 6;            // 0..7
#pragma unroll
            for (int mi = 0; mi < 4; ++mi) {
                const int gmb = m0 + mi * 16 + 4 * lg;
                const int dbase = n0 + lr;
                const float b0_ = bias[dbase], b1_ = bias[dbase + 16],
                            b2_ = bias[dbase + 32], b3_ = bias[dbase + 48];
#pragma unroll
                for (int i = 0; i < 4; ++i) {
                    const int row = gmb + i;
                    const float p0 = SIGM(acc[mi][0][i] + b0_);
                    const float p1 = SIGM(acc[mi][1][i] + b1_);
                    const float p2 = SIGM(acc[mi][2][i] + b2_);
                    const float p3 = SIGM(acc[mi][3][i] + b3_);
                    bf16* ob = (bf16*)Cout + (size_t)row * 2048;
                    ob[(size_t)dbase * 4]        = (bf16)(1.f - p0);
                    ob[(size_t)(dbase + 16) * 4] = (bf16)(1.f - p1);
                    ob[(size_t)(dbase + 32) * 4] = (bf16)(1.f - p2);
                    ob[(size_t)(dbase + 48) * 4] = (bf16)(1.f - p3);
                    float s_ = p0 + p1 + p2 + p3;
                    s_ += __shfl_xor(s_, 1); s_ += __shfl_xor(s_, 2);
                    s_ += __shfl_xor(s_, 4); s_ += __shfl_xor(s_, 8);
                    if (lr == 0) ((float*)Cout2)[(size_t)pidx * MM + row] = s_;
                }
            }
        } else {
#pragma unroll
            for (int mi = 0; mi < 4; ++mi)
#pragma unroll
                for (int ni = 0; ni < 4; ++ni) {
                    const int gmb = m0 + mi * 16 + 4 * lg;
                    const int gn = n0 + ni * 16 + lr;
                    const int dn = gn & 511;
                    const float bia = bias[gn];
#pragma unroll
                    for (int i = 0; i < 4; ++i)
                        ((bf16*)Cout)[((size_t)(gmb + i) * 512 + dn) * 4 + cls] =
                            (bf16)(acc[mi][ni][i] + bia);
                }
        }
    } else {
#pragma unroll
        for (int mi = 0; mi < 4; ++mi)
#pragma unroll
            for (int ni = 0; ni < 4; ++ni) {
                const int gmb = m0 + mi * 16 + 4 * lg;
                const int gn = n0 + ni * 16 + lr;
                const float bia = bias[gn];
#pragma unroll
                for (int i = 0; i < 4; ++i) {
                    const float v = acc[mi][ni][i] + bia;
                    const float ge = 0.5f * v * (1.0f + erff(v * 0.70710678118654752f));
                    ((bf16*)Cout)[(size_t)(gmb + i) * N + gn] = (bf16)ge;
                }
            }
    }
}

// ---------------------------------------------------------------- GEMM 128x128 tri (R12, FFN2 control)
template <int MODE>
__global__ __launch_bounds__(256) void gemm_bt(
    const bf16* __restrict__ A, const bf16* __restrict__ Bt,
    const float* __restrict__ bias, void* __restrict__ Cout,
    const float* __restrict__ add1, const float* __restrict__ add2,
    int M, int N, int K) {
    __shared__ bf16 As[3][4096];
    __shared__ bf16 Bs[3][4096];
    const int tid = threadIdx.x;
    const int lane = tid & 63;
    const int wv = tid >> 6;
    const int wr = wv >> 1, wc = wv & 1;
    const int nb = N >> 7;
    const int nwg = gridDim.x;
    int bx = blockIdx.x;
    if ((nwg & 7) == 0) bx = (bx & 7) * (nwg >> 3) + (bx >> 3);
    const int bm = bx / nb, bn = bx % nb;
    const int m0 = bm << 7, n0 = bn << 7;

    const int srow = tid >> 2;
    const int scol = (((tid & 3) ^ ((tid >> 3) & 3)) << 3);
    const bf16* Asrc = A + (size_t)(m0 + srow) * K + scol;
    const bf16* Bsrc = Bt + (size_t)(n0 + srow) * K + scol;
    const size_t rstep = (size_t)64 * K;

    const int lr = lane & 15, lg = lane >> 4;
    const int sel = ((lg ^ ((lr >> 1) & 3)) << 3);
    const int aoff = (wr * 64 + lr) * 32 + sel;
    const int boff = (wc * 64 + lr) * 32 + sel;

#define STG(buf, k0)                                                \
    do {                                                            \
        gl_lds16(Asrc + (k0),         &As[buf][wv * 512]);          \
        gl_lds16(Asrc + (k0) + rstep, &As[buf][wv * 512 + 2048]);   \
        gl_lds16(Bsrc + (k0),         &Bs[buf][wv * 512]);          \
        gl_lds16(Bsrc + (k0) + rstep, &Bs[buf][wv * 512 + 2048]);   \
    } while (0)

    f32x4 acc00 = {}, acc01 = {}, acc02 = {}, acc03 = {};
    f32x4 acc10 = {}, acc11 = {}, acc12 = {}, acc13 = {};
    f32x4 acc20 = {}, acc21 = {}, acc22 = {}, acc23 = {};
    f32x4 acc30 = {}, acc31 = {}, acc32 = {}, acc33 = {};

    const int NT = K >> 5;
    STG(0, 0);
    STG(1, 32);
    int cur = 0;
    for (int t = 0; t < NT; ++t) {
        if (t + 1 < NT) asm volatile("s_waitcnt vmcnt(4)" ::: "memory");
        else            asm volatile("s_waitcnt vmcnt(0)" ::: "memory");
        __builtin_amdgcn_s_barrier();
        asm volatile("" ::: "memory");
        const bf16* Ab = As[cur];
        const bf16* Bb = Bs[cur];
        bf16x8 af0 = *(const bf16x8*)&Ab[aoff];
        bf16x8 af1 = *(const bf16x8*)&Ab[aoff + 512];
        bf16x8 af2 = *(const bf16x8*)&Ab[aoff + 1024];
        bf16x8 af3 = *(const bf16x8*)&Ab[aoff + 1536];
        bf16x8 bf0 = *(const bf16x8*)&Bb[boff];
        bf16x8 bf1 = *(const bf16x8*)&Bb[boff + 512];
        bf16x8 bf2 = *(const bf16x8*)&Bb[boff + 1024];
        bf16x8 bf3 = *(const bf16x8*)&Bb[boff + 1536];
        if (t + 2 < NT) {
            const int stg = (cur == 0) ? 2 : cur - 1;
            STG(stg, (t + 2) << 5);
        }
        MF(af0, bf0, acc00); MF(af0, bf1, acc01); MF(af0, bf2, acc02); MF(af0, bf3, acc03);
        MF(af1, bf0, acc10); MF(af1, bf1, acc11); MF(af1, bf2, acc12); MF(af1, bf3, acc13);
        MF(af2, bf0, acc20); MF(af2, bf1, acc21); MF(af2, bf2, acc22); MF(af2, bf3, acc23);
        MF(af3, bf0, acc30); MF(af3, bf1, acc31); MF(af3, bf2, acc32); MF(af3, bf3, acc33);
        cur = (cur == 2) ? 0 : cur + 1;
    }
#undef STG

#define EPI(mi, ni, ACC)                                                        \
    do {                                                                        \
        const int gmb = m0 + wr * 64 + mi * 16 + 4 * lg;                        \
        const int gn = n0 + wc * 64 + ni * 16 + lr;                             \
        const float bia = bias[gn];                                             \
        _Pragma("unroll")                                                       \
        for (int i = 0; i < 4; ++i) {                                           \
            float v = ACC[i] + bia;                                             \
            const size_t off = (size_t)(gmb + i) * N + gn;                      \
            ((float*)Cout)[off] = v + add1[off] + add2[off];                    \
        }                                                                       \
    } while (0)
    EPI(0, 0, acc00); EPI(0, 1, acc01); EPI(0, 2, acc02); EPI(0, 3, acc03);
    EPI(1, 0, acc10); EPI(1, 1, acc11); EPI(1, 2, acc12); EPI(1, 3, acc13);
    EPI(2, 0, acc20); EPI(2, 1, acc21); EPI(2, 2, acc22); EPI(2, 3, acc23);
    EPI(3, 0, acc30); EPI(3, 1, acc31); EPI(3, 2, acc32); EPI(3, 3, acc33);
#undef EPI
}

// ---------------------------------------------------------------- p_scalar finalize
__global__ __launch_bounds__(256) void pscalar_fin(const float* __restrict__ part,
                                                   float* __restrict__ ps) {
    const int i = blockIdx.x * 256 + threadIdx.x;   // 16384 rows
    float s = 0.f;
#pragma unroll
    for (int j = 0; j < 8; ++j) s += part[(size_t)j * MM + i];
    ps[i] = s * (1.f / 512.f);
}

// ---------------------------------------------------------------- scan (ILP x2)
// 13-stage pipeline DP; each thread runs TWO independent pipelines (chunks
// 2c, 2c+1) to double per-wave issue density (scan is issue/dep-bound at
// 2 waves/SIMD). h_mean partials fused (one atomicAdd per thread).
#define SCL 32
#define STAGE13(par, pai, pbr, pbi, car, cai, br_, bi_)                     \
    _Pragma("unroll")                                                       \
    for (int k = 0; k < 13; ++k) {                                          \
        const float tar = par[k], tai = pai[k], tbr = pbr[k], tbi = pbi[k]; \
        par[k] = car; pai[k] = cai; pbr[k] = br_; pbi[k] = bi_;             \
        const float nbr = car * tbr - cai * tbi + br_;                      \
        const float nbi = car * tbi + cai * tbr + bi_;                      \
        if (k < 12) {                                                       \
            const float nar = car * tar - cai * tai;                        \
            const float nai = car * tai + cai * tar;                        \
            car = nar; cai = nai;                                           \
        }                                                                   \
        br_ = nbr; bi_ = nbi;                                               \
    }

#define XF(tp, car, cai, br_, bi_)                                       \
    {                                                                    \
        const bf16x4 q_ = *(const bf16x4*)(tp);                          \
        (tp) += 2048;                                                    \
        const float om_ = (float)q_[0];                                  \
        const float th_ = (float)q_[1];                                  \
        br_ = (float)q_[2];                                              \
        bi_ = (float)q_[3];                                              \
        float fr_, sn_, cs_;                                             \
        const float rv_ = th_ * 0.15915494309189535f;                    \
        asm("v_fract_f32 %0, %1" : "=v"(fr_) : "v"(rv_));                \
        asm("v_sin_f32 %0, %1" : "=v"(sn_) : "v"(fr_));                  \
        asm("v_cos_f32 %0, %1" : "=v"(cs_) : "v"(fr_));                  \
        car = om_ * cs_; cai = om_ * sn_;                                \
    }

__global__ __launch_bounds__(256) void scan_kernel(const bf16* __restrict__ lint4,
                                                   float* __restrict__ h_re,
                                                   float* __restrict__ hsum) {
    const int blk = blockIdx.x;          // 512 blocks
    const int b = blk >> 7;
    const int rem = blk & 127;
    const int dh = rem & 1;
    const int tcp = rem >> 1;            // 0..63
    const int d = dh * 256 + threadIdx.x;
    const int t0a = tcp * 64;
    const int t0b = t0a + 32;

    float parA[13], paiA[13], pbrA[13], pbiA[13];
    float parB[13], paiB[13], pbrB[13], pbiB[13];
#pragma unroll
    for (int k = 0; k < 13; ++k) {
        parA[k] = 0.f; paiA[k] = 0.f; pbrA[k] = 0.f; pbiA[k] = 0.f;
        parB[k] = 0.f; paiB[k] = 0.f; pbrB[k] = 0.f; pbiB[k] = 0.f;
    }

    const int warmA = (tcp == 0) ? 0 : 13;
    const bf16* tpA = lint4 + ((size_t)(b * TT + t0a - warmA) * 512 + d) * 4;
    const bf16* tpB = lint4 + ((size_t)(b * TT + t0b - 13) * 512 + d) * 4;
    float* poutA = h_re + ((size_t)(b * TT + t0a)) * DD + d;
    float* poutB = h_re + ((size_t)(b * TT + t0b)) * DD + d;

    float carA, caiA, brA, biA, carB, caiB, brB, biB;
    for (int s = 0; s < 13; ++s) {
        if (tcp != 0) {           // wave-uniform
            XF(tpA, carA, caiA, brA, biA)
            STAGE13(parA, paiA, pbrA, pbiA, carA, caiA, brA, biA)
        }
        XF(tpB, carB, caiB, brB, biB)
        STAGE13(parB, paiB, pbrB, pbiB, carB, caiB, brB, biB)
    }

    float hacc = 0.f;
#pragma unroll 2
    for (int s = 0; s < SCL; ++s) {
        XF(tpA, carA, caiA, brA, biA)
        if (tcp == 0 && s == 0) {
#pragma unroll
            for (int k = 0; k < 13; ++k) { parA[k] = carA; paiA[k] = caiA; pbrA[k] = brA; pbiA[k] = biA; }
        } else {
            STAGE13(parA, paiA, pbrA, pbiA, carA, caiA, brA, biA)
        }
        poutA[(size_t)s * DD] = brA;
        hacc += brA;
        XF(tpB, carB, caiB, brB, biB)
        STAGE13(parB, paiB, pbrB, pbiB, carB, caiB, brB, biB)
        poutB[(size_t)s * DD] = brB;
        hacc += brB;
    }
    atomicAdd(&hsum[b * DD + d], hacc);
}
#undef XF
#undef STAGE13

// ---------------------------------------------------------------- top-16
__global__ __launch_bounds__(256) void topk_kernel(const float* __restrict__ ps,
                                                   int* __restrict__ idx_out) {
    __shared__ float vals[TT];
    __shared__ float rv[4];
    __shared__ int ri[4];
    const int b = blockIdx.x, tid = threadIdx.x;
    for (int i = tid; i < TT; i += 256) vals[i] = ps[b * TT + i];
    __syncthreads();
    for (int kk = 0; kk < 16; ++kk) {
        float bv = -1e30f; int bi = 0x7fffffff;
        for (int i = tid; i < TT; i += 256) {
            const float v = vals[i];
            if (v > bv || (v == bv && i < bi)) { bv = v; bi = i; }
        }
#pragma unroll
        for (int o = 32; o; o >>= 1) {
            const float ov = __shfl_down(bv, o);
            const int oi = __shfl_down(bi, o);
            if (ov > bv || (ov == bv && oi < bi)) { bv = ov; bi = oi; }
        }
        const int lane = tid & 63, wid = tid >> 6;
        if (!lane) { rv[wid] = bv; ri[wid] = bi; }
        __syncthreads();
        if (!tid) {
            float fbv = rv[0]; int fbi = ri[0];
            for (int w = 1; w < 4; ++w)
                if (rv[w] > fbv || (rv[w] == fbv && ri[w] < fbi)) { fbv = rv[w]; fbi = ri[w]; }
            idx_out[b * 16 + kk] = fbi;
            vals[fbi] = -1e30f;
        }
        __syncthreads();
    }
}

// ---------------------------------------------------------------- keys/values
__global__ __launch_bounds__(256) void kv_kernel(
    const float* __restrict__ h_re, const int* __restrict__ tki,
    const float* __restrict__ Wk, const float* __restrict__ Wkb,
    const float* __restrict__ Wv, const float* __restrict__ Wvb,
    float* __restrict__ keys, float* __restrict__ vals) {
    const int blk = blockIdx.x;
    const int b = blk >> 4, j = blk & 15;
    const int tid = threadIdx.x;
    __shared__ float hrow[512];
    const int row = tki[b * 16 + j];
    for (int i = tid; i < 512; i += 256)
        hrow[i] = h_re[((size_t)(b * TT + row)) * DD + i];
    __syncthreads();
    for (int n = tid; n < 512; n += 256) {
        float sk = Wkb[n], sv = Wvb[n];
        for (int k = 0; k < 512; ++k) {
            const float h = hrow[k];
            sk += h * Wk[(size_t)k * 512 + n];
            sv += h * Wv[(size_t)k * 512 + n];
        }
        keys[((size_t)(b * 16 + j)) * 512 + n] = sk;
        vals[((size_t)(b * 16 + j)) * 512 + n] = sv;
    }
}

// ---------------------------------------------------------------- query/gate/attn/out
__global__ __launch_bounds__(256) void attn_out_kernel(
    const float* __restrict__ hsum, const float* __restrict__ Wq,
    const float* __restrict__ Wqb, const float* __restrict__ gw,
    const float* __restrict__ gb, const float* __restrict__ keys,
    const float* __restrict__ vals, float* __restrict__ out1) {
    const int b = blockIdx.x, tid = threadIdx.x;
    const int lane = tid & 63, wid = tid >> 6;
    __shared__ float hm[512];
    __shared__ float q[512];
    __shared__ float sc[16];
    __shared__ float red[4];
    for (int d0 = tid; d0 < 512; d0 += 256)
        hm[d0] = hsum[b * 512 + d0] * (1.f / 4096.f);
    __syncthreads();
    for (int n = tid; n < 512; n += 256) {
        float s = Wqb[n];
        for (int k = 0; k < 512; ++k) s += hm[k] * Wq[(size_t)k * 512 + n];
        q[n] = s;
    }
    float gp = 0.f;
    for (int k = tid; k < 512; k += 256) gp += hm[k] * gw[k];
#pragma unroll
    for (int o = 32; o; o >>= 1) gp += __shfl_down(gp, o);
    if (!lane) red[wid] = gp;
    __syncthreads();
    const float g = 1.f / (1.f + __expf(-(red[0] + red[1] + red[2] + red[3] + gb[0])));
    for (int kk = wid; kk < 16; kk += 4) {
        float sp = 0.f;
        const float* kr = keys + ((size_t)(b * 16 + kk)) * 512;
        for (int k2 = lane; k2 < 512; k2 += 64) sp += q[k2] * kr[k2];
#pragma unroll
        for (int o = 32; o; o >>= 1) sp += __shfl_down(sp, o);
        if (!lane) sc[kk] = sp * 0.04419417382415922f;
    }
    __syncthreads();
    float mx = sc[0];
#pragma unroll
    for (int kk = 1; kk < 16; ++kk) mx = fmaxf(mx, sc[kk]);
    float den = 0.f;
    float w16[16];
#pragma unroll
    for (int kk = 0; kk < 16; ++kk) { w16[kk] = __expf(sc[kk] - mx); den += w16[kk]; }
    const float rden = 1.f / den;
    for (int d0 = tid; d0 < 512; d0 += 256) {
        float co = 0.f;
#pragma unroll
        for (int kk = 0; kk < 16; ++kk)
            co += w16[kk] * vals[((size_t)(b * 16 + kk)) * 512 + d0];
        out1[b * 512 + d0] = hm[d0] + g * (co * rden);
    }
}

// ---------------------------------------------------------------- launch
extern "C" void kernel_launch(void* const* d_in, const int* in_sizes, int n_in,
                              void* d_out, int out_size, void* d_ws, size_t ws_size,
                              hipStream_t stream) {
    const float* x    = (const float*)d_in[0];
    const float* ln1g = (const float*)d_in[1];
    const float* ln1b = (const float*)d_in[2];
    const float* ln2g = (const float*)d_in[3];
    const float* ln2b = (const float*)d_in[4];
    const float* Wp_w = (const float*)d_in[5];
    const float* Wp_b = (const float*)d_in[6];
    const float* Wt_w = (const float*)d_in[7];
    const float* Wt_b = (const float*)d_in[8];
    const float* Wr_w = (const float*)d_in[9];
    const float* Wr_b = (const float*)d_in[10];
    const float* Wi_w = (const float*)d_in[11];
    const float* Wi_b = (const float*)d_in[12];
    const float* Wk_w = (const float*)d_in[13];
    const float* Wk_b = (const float*)d_in[14];
    const float* Wv_w = (const float*)d_in[15];
    const float* Wv_b = (const float*)d_in[16];
    const float* Wq_w = (const float*)d_in[17];
    const float* Wq_b = (const float*)d_in[18];
    const float* gw   = (const float*)d_in[19];
    const float* gb   = (const float*)d_in[20];
    const float* f1w  = (const float*)d_in[21];
    const float* f1b  = (const float*)d_in[22];
    const float* f2w  = (const float*)d_in[23];
    const float* f2b  = (const float*)d_in[24];

    char* wsp = (char*)d_ws;
    bf16* lint4 = (bf16*)wsp;                        // [M][512][4] bf16 (67MB)
    char* p = wsp + 67108864;
    float* h_re = (float*)p; p += 33554432;          // [M][512] f32
    bf16* xn = (bf16*)p;     p += 16777216;          // [M][512] bf16
    bf16* hn = (bf16*)p;     p += 16777216;          // [M][512] bf16
    bf16* wcat = (bf16*)p;   p += 2097152;           // [2048][512] bf16 (Bt)
    bf16* f1bt = (bf16*)p;   p += 2097152;           // [2048][512] bf16
    bf16* f2bt = (bf16*)p;   p += 2097152;           // [512][2048] bf16
    float* bcat = (float*)p; p += 8192;              // [2048]
    float* ps = (float*)p;   p += 65536;             // [B][T]
    float* pspart = (float*)p; p += 524288;          // [8][M]
    float* hsum = (float*)p; p += 8192;              // [B][512]
    int* tki = (int*)p;      p += 256;               // [B][16]
    float* keys = (float*)p; p += 131072;            // [B][16][512]
    float* valsb = (float*)p;                        // [B][16][512]
    bf16* act = (bf16*)wsp;                          // [M][2048] bf16 overlays lint4
    float* out0 = (float*)d_out;
    float* out1 = (float*)d_out + OUT1_OFF;

    dim3 tb(32, 8);
    transpose_bf16<<<dim3(16, 16), tb, 0, stream>>>(Wp_w, wcat + (size_t)0 * 512 * 512, 512, 512);
    transpose_bf16<<<dim3(16, 16), tb, 0, stream>>>(Wt_w, wcat + (size_t)1 * 512 * 512, 512, 512);
    transpose_bf16<<<dim3(16, 16), tb, 0, stream>>>(Wr_w, wcat + (size_t)2 * 512 * 512, 512, 512);
    transpose_bf16<<<dim3(16, 16), tb, 0, stream>>>(Wi_w, wcat + (size_t)3 * 512 * 512, 512, 512);
    transpose_bf16<<<dim3(64, 16), tb, 0, stream>>>(f1w, f1bt, 512, 2048);
    transpose_bf16<<<dim3(16, 64), tb, 0, stream>>>(f2w, f2bt, 2048, 512);
    pack_bias<<<8, 256, 0, stream>>>(Wp_b, Wt_b, Wr_b, Wi_b, bcat);

    // LN1 -> xn
    ln_kernel<<<4096, 256, 0, stream>>>(x, nullptr, ln1g, ln1b, xn);
    // fused 4-projection GEMM (1-wave + swizzle) -> lint4; pscalar partials
    gemm_wv<0><<<8192, 64, 0, stream>>>(xn, wcat, bcat, lint4, pspart, MM, 2048, 512);
    // p_scalar finalize
    pscalar_fin<<<64, 256, 0, stream>>>(pspart, ps);
    // zero hsum, then scan (ILP x2, h_mean fused)
    zero_kernel<<<8, 256, 0, stream>>>(hsum, 2048);
    scan_kernel<<<512, 256, 0, stream>>>(lint4, h_re, hsum);
    // cache path
    topk_kernel<<<4, 256, 0, stream>>>(ps, tki);
    kv_kernel<<<64, 256, 0, stream>>>(h_re, tki, Wk_w, Wk_b, Wv_w, Wv_b, keys, valsb);
    attn_out_kernel<<<4, 256, 0, stream>>>(hsum, Wq_w, Wq_b, gw, gb, keys, valsb, out1);
    // FFN path (act overlays lint4 -- safe: scan already consumed it)
    ln_kernel<<<4096, 256, 0, stream>>>(h_re, x, ln2g, ln2b, hn);
    gemm_wv<1><<<8192, 64, 0, stream>>>(hn, f1bt, f1b, act, nullptr, MM, 2048, 512);
    gemm_bt<2><<<512, 256, 0, stream>>>(act, f2bt, f2b, out0, h_re, x, MM, 512, 2048);
}

// Round 14
// 404.816 us; speedup vs baseline: 1.1314x; 1.1314x over previous
//
#include <hip/hip_runtime.h>
#include <hip/hip_bf16.h>
#include <cstdint>
#include <cstddef>

typedef __bf16 bf16;
typedef __attribute__((ext_vector_type(8))) __bf16 bf16x8;
typedef __attribute__((ext_vector_type(4))) __bf16 bf16x4;
typedef __attribute__((ext_vector_type(4))) float f32x4;

#define BB 4
#define TT 4096
#define DD 512
#define MM (BB * TT)              // 16384 rows
#define OUT1_OFF ((size_t)MM * DD)

typedef __attribute__((address_space(1))) void as1_void;
typedef __attribute__((address_space(3))) void as3_void;

__device__ __forceinline__ void gl_lds16(const void* g, void* l) {
    __builtin_amdgcn_global_load_lds((as1_void*)(uintptr_t)g,
                                     (as3_void*)(uintptr_t)l, 16, 0, 0);
}

#define SIGM(x) (__builtin_amdgcn_rcpf(1.f + __expf(-(x))))

// ---------------------------------------------------------------- transpose
__global__ void transpose_bf16(const float* __restrict__ in, bf16* __restrict__ out,
                               int R, int C) {
    __shared__ float tile[32][33];
    const int c0 = blockIdx.x * 32, r0 = blockIdx.y * 32;
    const int tx = threadIdx.x, ty = threadIdx.y;
#pragma unroll
    for (int i = 0; i < 32; i += 8)
        tile[ty + i][tx] = in[(size_t)(r0 + ty + i) * C + (c0 + tx)];
    __syncthreads();
#pragma unroll
    for (int i = 0; i < 32; i += 8)
        out[(size_t)(c0 + ty + i) * R + (r0 + tx)] = (bf16)tile[tx][ty + i];
}

__global__ void pack_bias(const float* __restrict__ a, const float* __restrict__ b,
                          const float* __restrict__ c, const float* __restrict__ d,
                          float* __restrict__ o) {
    const int i = blockIdx.x * 256 + threadIdx.x;
    if (i < 2048) {
        const float* s = (i < 512) ? a : (i < 1024) ? b : (i < 1536) ? c : d;
        o[i] = s[i & 511];
    }
}

__global__ void zero_kernel(float* __restrict__ p, int n) {
    const int i = blockIdx.x * 256 + threadIdx.x;
    if (i < n) p[i] = 0.f;
}

// ---------------------------------------------------------------- layernorm
// out = LN(X [+ Xadd_bf16]) * g + b  (Xadd is bf16 h_re)
__global__ __launch_bounds__(256) void ln_kernel(
    const float* __restrict__ X, const bf16* __restrict__ Xadd,
    const float* __restrict__ gw, const float* __restrict__ bw,
    bf16* __restrict__ out) {
    const int row = blockIdx.x * 4 + (threadIdx.x >> 6);
    const int lane = threadIdx.x & 63;
    const float* xr = X + (size_t)row * DD + lane * 8;
    float v[8];
    float4 v0 = *(const float4*)xr;
    float4 v1 = *(const float4*)(xr + 4);
    v[0] = v0.x; v[1] = v0.y; v[2] = v0.z; v[3] = v0.w;
    v[4] = v1.x; v[5] = v1.y; v[6] = v1.z; v[7] = v1.w;
    if (Xadd) {
        const bf16x8 a8 = *(const bf16x8*)(Xadd + (size_t)row * DD + lane * 8);
#pragma unroll
        for (int i = 0; i < 8; ++i) v[i] += (float)a8[i];
    }
    float s = 0.f, ss = 0.f;
#pragma unroll
    for (int i = 0; i < 8; ++i) { s += v[i]; ss += v[i] * v[i]; }
#pragma unroll
    for (int o = 32; o; o >>= 1) { s += __shfl_down(s, o); ss += __shfl_down(ss, o); }
    s = __shfl(s, 0); ss = __shfl(ss, 0);
    const float mu = s * (1.f / DD);
    const float var = ss * (1.f / DD) - mu * mu;
    const float rstd = rsqrtf(var + 1e-5f);
    bf16x8 o8;
#pragma unroll
    for (int i = 0; i < 8; ++i)
        o8[i] = (bf16)((v[i] - mu) * rstd * gw[lane * 8 + i] + bw[lane * 8 + i]);
    *(bf16x8*)(out + (size_t)row * DD + lane * 8) = o8;
}

#define MF(a_, b_, c_) c_ = __builtin_amdgcn_mfma_f32_16x16x32_bf16(a_, b_, c_, 0, 0, 0)

// ---------------------------------------------------------------- GEMM (bf16 MFMA)
// R12-proven: 128x128/4-wave/BK=32, tri-buffered counted-vmcnt, ONE barrier
// per K-step, T2 both-sides XOR swizzle.
// MODE 0: fused transform epilogue (lint4 {om,th,re,im} + pscalar partials)
// MODE 1: bf16 out = gelu(acc + bias)
// MODE 2: f32 out = acc + bias + add1(bf16 h_re) + add2(f32 x)
template <int MODE>
__global__ __launch_bounds__(256) void gemm_bt(
    const bf16* __restrict__ A, const bf16* __restrict__ Bt,
    const float* __restrict__ bias, void* __restrict__ Cout,
    void* __restrict__ Cout2,
    const bf16* __restrict__ add1, const float* __restrict__ add2,
    int M, int N, int K) {
    __shared__ bf16 As[3][4096];
    __shared__ bf16 Bs[3][4096];
    const int tid = threadIdx.x;
    const int lane = tid & 63;
    const int wv = tid >> 6;
    const int wr = wv >> 1, wc = wv & 1;
    const int nb = N >> 7;
    const int nwg = gridDim.x;
    int bx = blockIdx.x;
    if ((nwg & 7) == 0) bx = (bx & 7) * (nwg >> 3) + (bx >> 3);  // XCD swizzle
    const int bm = bx / nb, bn = bx % nb;
    const int m0 = bm << 7, n0 = bn << 7;

    const int srow = tid >> 2;                              // staging row (0..63)
    const int scol = (((tid & 3) ^ ((tid >> 3) & 3)) << 3); // pre-swizzled global col
    const bf16* Asrc = A + (size_t)(m0 + srow) * K + scol;
    const bf16* Bsrc = Bt + (size_t)(n0 + srow) * K + scol;
    const size_t rstep = (size_t)64 * K;

    const int lr = lane & 15, lg = lane >> 4;
    const int sel = ((lg ^ ((lr >> 1) & 3)) << 3);          // swizzled 16B slot
    const int aoff = (wr * 64 + lr) * 32 + sel;
    const int boff = (wc * 64 + lr) * 32 + sel;

#define STG(buf, k0)                                                \
    do {                                                            \
        gl_lds16(Asrc + (k0),         &As[buf][wv * 512]);          \
        gl_lds16(Asrc + (k0) + rstep, &As[buf][wv * 512 + 2048]);   \
        gl_lds16(Bsrc + (k0),         &Bs[buf][wv * 512]);          \
        gl_lds16(Bsrc + (k0) + rstep, &Bs[buf][wv * 512 + 2048]);   \
    } while (0)

    f32x4 acc00 = {}, acc01 = {}, acc02 = {}, acc03 = {};
    f32x4 acc10 = {}, acc11 = {}, acc12 = {}, acc13 = {};
    f32x4 acc20 = {}, acc21 = {}, acc22 = {}, acc23 = {};
    f32x4 acc30 = {}, acc31 = {}, acc32 = {}, acc33 = {};

    const int NT = K >> 5;
    STG(0, 0);
    STG(1, 32);
    int cur = 0;                 // buffer of tile t (t % 3)
    for (int t = 0; t < NT; ++t) {
        if (t + 1 < NT) asm volatile("s_waitcnt vmcnt(4)" ::: "memory");
        else            asm volatile("s_waitcnt vmcnt(0)" ::: "memory");
        __builtin_amdgcn_s_barrier();
        asm volatile("" ::: "memory");
        const bf16* Ab = As[cur];
        const bf16* Bb = Bs[cur];
        bf16x8 af0 = *(const bf16x8*)&Ab[aoff];
        bf16x8 af1 = *(const bf16x8*)&Ab[aoff + 512];
        bf16x8 af2 = *(const bf16x8*)&Ab[aoff + 1024];
        bf16x8 af3 = *(const bf16x8*)&Ab[aoff + 1536];
        bf16x8 bf0 = *(const bf16x8*)&Bb[boff];
        bf16x8 bf1 = *(const bf16x8*)&Bb[boff + 512];
        bf16x8 bf2 = *(const bf16x8*)&Bb[boff + 1024];
        bf16x8 bf3 = *(const bf16x8*)&Bb[boff + 1536];
        if (t + 2 < NT) {
            const int stg = (cur == 0) ? 2 : cur - 1;
            STG(stg, (t + 2) << 5);
        }
        MF(af0, bf0, acc00); MF(af0, bf1, acc01); MF(af0, bf2, acc02); MF(af0, bf3, acc03);
        MF(af1, bf0, acc10); MF(af1, bf1, acc11); MF(af1, bf2, acc12); MF(af1, bf3, acc13);
        MF(af2, bf0, acc20); MF(af2, bf1, acc21); MF(af2, bf2, acc22); MF(af2, bf3, acc23);
        MF(af3, bf0, acc30); MF(af3, bf1, acc31); MF(af3, bf2, acc32); MF(af3, bf3, acc33);
        cur = (cur == 2) ? 0 : cur + 1;
    }
#undef STG

    if constexpr (MODE == 0) {
        const int cls = n0 >> 9;                 // 0=p 1=theta 2=re 3=im
        if (cls == 0) {
            const int pidx = (n0 + wc * 64) >> 6;    // 0..7
#define EPI0(mi, A0, A1, A2, A3)                                              \
    do {                                                                      \
        const int gmb = m0 + wr * 64 + mi * 16 + 4 * lg;                      \
        const int dbase = n0 + wc * 64 + lr;                                  \
        const float b0_ = bias[dbase], b1_ = bias[dbase + 16],                \
                    b2_ = bias[dbase + 32], b3_ = bias[dbase + 48];           \
        _Pragma("unroll")                                                     \
        for (int i = 0; i < 4; ++i) {                                         \
            const int row = gmb + i;                                          \
            const float p0 = SIGM(A0[i] + b0_);                               \
            const float p1 = SIGM(A1[i] + b1_);                               \
            const float p2 = SIGM(A2[i] + b2_);                               \
            const float p3 = SIGM(A3[i] + b3_);                               \
            bf16* ob = (bf16*)Cout + (size_t)row * 2048;                      \
            ob[(size_t)dbase * 4]        = (bf16)(1.f - p0);                  \
            ob[(size_t)(dbase + 16) * 4] = (bf16)(1.f - p1);                  \
            ob[(size_t)(dbase + 32) * 4] = (bf16)(1.f - p2);                  \
            ob[(size_t)(dbase + 48) * 4] = (bf16)(1.f - p3);                  \
            float s_ = p0 + p1 + p2 + p3;                                     \
            s_ += __shfl_xor(s_, 1); s_ += __shfl_xor(s_, 2);                 \
            s_ += __shfl_xor(s_, 4); s_ += __shfl_xor(s_, 8);                 \
            if (lr == 0) ((float*)Cout2)[(size_t)pidx * MM + row] = s_;       \
        }                                                                     \
    } while (0)
            EPI0(0, acc00, acc01, acc02, acc03);
            EPI0(1, acc10, acc11, acc12, acc13);
            EPI0(2, acc20, acc21, acc22, acc23);
            EPI0(3, acc30, acc31, acc32, acc33);
#undef EPI0
        } else {
#define EPIS(mi, ni, ACC)                                                     \
    do {                                                                      \
        const int gmb = m0 + wr * 64 + mi * 16 + 4 * lg;                      \
        const int gn = n0 + wc * 64 + ni * 16 + lr;                           \
        const int dn = gn & 511;                                              \
        const float bia = bias[gn];                                           \
        _Pragma("unroll")                                                     \
        for (int i = 0; i < 4; ++i)                                           \
            ((bf16*)Cout)[((size_t)(gmb + i) * 512 + dn) * 4 + cls] =         \
                (bf16)(ACC[i] + bia);                                         \
    } while (0)
            EPIS(0, 0, acc00); EPIS(0, 1, acc01); EPIS(0, 2, acc02); EPIS(0, 3, acc03);
            EPIS(1, 0, acc10); EPIS(1, 1, acc11); EPIS(1, 2, acc12); EPIS(1, 3, acc13);
            EPIS(2, 0, acc20); EPIS(2, 1, acc21); EPIS(2, 2, acc22); EPIS(2, 3, acc23);
            EPIS(3, 0, acc30); EPIS(3, 1, acc31); EPIS(3, 2, acc32); EPIS(3, 3, acc33);
#undef EPIS
        }
    } else {
#define EPI(mi, ni, ACC)                                                        \
    do {                                                                        \
        const int gmb = m0 + wr * 64 + mi * 16 + 4 * lg;                        \
        const int gn = n0 + wc * 64 + ni * 16 + lr;                             \
        const float bia = bias[gn];                                             \
        _Pragma("unroll")                                                       \
        for (int i = 0; i < 4; ++i) {                                           \
            float v = ACC[i] + bia;                                             \
            const int row = gmb + i;                                            \
            if (MODE == 1) {                                                    \
                const float ge = 0.5f * v * (1.0f + erff(v * 0.70710678118654752f)); \
                ((bf16*)Cout)[(size_t)row * N + gn] = (bf16)ge;                 \
            } else {                                                            \
                const size_t off = (size_t)row * N + gn;                        \
                ((float*)Cout)[off] = v + (float)add1[off] + add2[off];         \
            }                                                                   \
        }                                                                       \
    } while (0)
        EPI(0, 0, acc00); EPI(0, 1, acc01); EPI(0, 2, acc02); EPI(0, 3, acc03);
        EPI(1, 0, acc10); EPI(1, 1, acc11); EPI(1, 2, acc12); EPI(1, 3, acc13);
        EPI(2, 0, acc20); EPI(2, 1, acc21); EPI(2, 2, acc22); EPI(2, 3, acc23);
        EPI(3, 0, acc30); EPI(3, 1, acc31); EPI(3, 2, acc32); EPI(3, 3, acc33);
#undef EPI
    }
}

// ---------------------------------------------------------------- p_scalar finalize
__global__ __launch_bounds__(256) void pscalar_fin(const float* __restrict__ part,
                                                   float* __restrict__ ps) {
    const int i = blockIdx.x * 256 + threadIdx.x;   // 16384 rows
    float s = 0.f;
#pragma unroll
    for (int j = 0; j < 8; ++j) s += part[(size_t)j * MM + i];
    ps[i] = s * (1.f / 512.f);
}

// ---------------------------------------------------------------- scan (ILP x2)
// 13-stage pipeline DP; each thread runs TWO independent pipelines.
// Output h_re in bf16 (halves write + downstream read traffic); h_mean
// partials accumulated in f32 BEFORE conversion (exact for attn path).
#define SCL 32
#define STAGE13(par, pai, pbr, pbi, car, cai, br_, bi_)                     \
    _Pragma("unroll")                                                       \
    for (int k = 0; k < 13; ++k) {                                          \
        const float tar = par[k], tai = pai[k], tbr = pbr[k], tbi = pbi[k]; \
        par[k] = car; pai[k] = cai; pbr[k] = br_; pbi[k] = bi_;             \
        const float nbr = car * tbr - cai * tbi + br_;                      \
        const float nbi = car * tbi + cai * tbr + bi_;                      \
        if (k < 12) {                                                       \
            const float nar = car * tar - cai * tai;                        \
            const float nai = car * tai + cai * tar;                        \
            car = nar; cai = nai;                                           \
        }                                                                   \
        br_ = nbr; bi_ = nbi;                                               \
    }

#define XF(tp, car, cai, br_, bi_)                                       \
    {                                                                    \
        const bf16x4 q_ = *(const bf16x4*)(tp);                          \
        (tp) += 2048;                                                    \
        const float om_ = (float)q_[0];                                  \
        const float th_ = (float)q_[1];                                  \
        br_ = (float)q_[2];                                              \
        bi_ = (float)q_[3];                                              \
        float fr_, sn_, cs_;                                             \
        const float rv_ = th_ * 0.15915494309189535f;                    \
        asm("v_fract_f32 %0, %1" : "=v"(fr_) : "v"(rv_));                \
        asm("v_sin_f32 %0, %1" : "=v"(sn_) : "v"(fr_));                  \
        asm("v_cos_f32 %0, %1" : "=v"(cs_) : "v"(fr_));                  \
        car = om_ * cs_; cai = om_ * sn_;                                \
    }

__global__ __launch_bounds__(256) void scan_kernel(const bf16* __restrict__ lint4,
                                                   bf16* __restrict__ h_re,
                                                   float* __restrict__ hsum) {
    const int blk = blockIdx.x;          // 512 blocks
    const int b = blk >> 7;
    const int rem = blk & 127;
    const int dh = rem & 1;
    const int tcp = rem >> 1;            // 0..63
    const int d = dh * 256 + threadIdx.x;
    const int t0a = tcp * 64;
    const int t0b = t0a + 32;

    float parA[13], paiA[13], pbrA[13], pbiA[13];
    float parB[13], paiB[13], pbrB[13], pbiB[13];
#pragma unroll
    for (int k = 0; k < 13; ++k) {
        parA[k] = 0.f; paiA[k] = 0.f; pbrA[k] = 0.f; pbiA[k] = 0.f;
        parB[k] = 0.f; paiB[k] = 0.f; pbrB[k] = 0.f; pbiB[k] = 0.f;
    }

    const int warmA = (tcp == 0) ? 0 : 13;
    const bf16* tpA = lint4 + ((size_t)(b * TT + t0a - warmA) * 512 + d) * 4;
    const bf16* tpB = lint4 + ((size_t)(b * TT + t0b - 13) * 512 + d) * 4;
    bf16* poutA = h_re + ((size_t)(b * TT + t0a)) * DD + d;
    bf16* poutB = h_re + ((size_t)(b * TT + t0b)) * DD + d;

    float carA, caiA, brA, biA, carB, caiB, brB, biB;
    for (int s = 0; s < 13; ++s) {
        if (tcp != 0) {           // wave-uniform
            XF(tpA, carA, caiA, brA, biA)
            STAGE13(parA, paiA, pbrA, pbiA, carA, caiA, brA, biA)
        }
        XF(tpB, carB, caiB, brB, biB)
        STAGE13(parB, paiB, pbrB, pbiB, carB, caiB, brB, biB)
    }

    float hacc = 0.f;
#pragma unroll 2
    for (int s = 0; s < SCL; ++s) {
        XF(tpA, carA, caiA, brA, biA)
        if (tcp == 0 && s == 0) {
#pragma unroll
            for (int k = 0; k < 13; ++k) { parA[k] = carA; paiA[k] = caiA; pbrA[k] = brA; pbiA[k] = biA; }
        } else {
            STAGE13(parA, paiA, pbrA, pbiA, carA, caiA, brA, biA)
        }
        poutA[(size_t)s * DD] = (bf16)brA;
        hacc += brA;
        XF(tpB, carB, caiB, brB, biB)
        STAGE13(parB, paiB, pbrB, pbiB, carB, caiB, brB, biB)
        poutB[(size_t)s * DD] = (bf16)brB;
        hacc += brB;
    }
    atomicAdd(&hsum[b * DD + d], hacc);
}
#undef XF
#undef STAGE13

// ---------------------------------------------------------------- top-16
__global__ __launch_bounds__(256) void topk_kernel(const float* __restrict__ ps,
                                                   int* __restrict__ idx_out) {
    __shared__ float vals[TT];
    __shared__ float rv[4];
    __shared__ int ri[4];
    const int b = blockIdx.x, tid = threadIdx.x;
    for (int i = tid; i < TT; i += 256) vals[i] = ps[b * TT + i];
    __syncthreads();
    for (int kk = 0; kk < 16; ++kk) {
        float bv = -1e30f; int bi = 0x7fffffff;
        for (int i = tid; i < TT; i += 256) {
            const float v = vals[i];
            if (v > bv || (v == bv && i < bi)) { bv = v; bi = i; }
        }
#pragma unroll
        for (int o = 32; o; o >>= 1) {
            const float ov = __shfl_down(bv, o);
            const int oi = __shfl_down(bi, o);
            if (ov > bv || (ov == bv && oi < bi)) { bv = ov; bi = oi; }
        }
        const int lane = tid & 63, wid = tid >> 6;
        if (!lane) { rv[wid] = bv; ri[wid] = bi; }
        __syncthreads();
        if (!tid) {
            float fbv = rv[0]; int fbi = ri[0];
            for (int w = 1; w < 4; ++w)
                if (rv[w] > fbv || (rv[w] == fbv && ri[w] < fbi)) { fbv = rv[w]; fbi = ri[w]; }
            idx_out[b * 16 + kk] = fbi;
            vals[fbi] = -1e30f;
        }
        __syncthreads();
    }
}

// ---------------------------------------------------------------- keys/values
__global__ __launch_bounds__(256) void kv_kernel(
    const bf16* __restrict__ h_re, const int* __restrict__ tki,
    const float* __restrict__ Wk, const float* __restrict__ Wkb,
    const float* __restrict__ Wv, const float* __restrict__ Wvb,
    float* __restrict__ keys, float* __restrict__ vals) {
    const int blk = blockIdx.x;
    const int b = blk >> 4, j = blk & 15;
    const int tid = threadIdx.x;
    __shared__ float hrow[512];
    const int row = tki[b * 16 + j];
    for (int i = tid; i < 512; i += 256)
        hrow[i] = (float)h_re[((size_t)(b * TT + row)) * DD + i];
    __syncthreads();
    for (int n = tid; n < 512; n += 256) {
        float sk = Wkb[n], sv = Wvb[n];
        for (int k = 0; k < 512; ++k) {
            const float h = hrow[k];
            sk += h * Wk[(size_t)k * 512 + n];
            sv += h * Wv[(size_t)k * 512 + n];
        }
        keys[((size_t)(b * 16 + j)) * 512 + n] = sk;
        vals[((size_t)(b * 16 + j)) * 512 + n] = sv;
    }
}

// ---------------------------------------------------------------- query/gate/attn/out
__global__ __launch_bounds__(256) void attn_out_kernel(
    const float* __restrict__ hsum, const float* __restrict__ Wq,
    const float* __restrict__ Wqb, const float* __restrict__ gw,
    const float* __restrict__ gb, const float* __restrict__ keys,
    const float* __restrict__ vals, float* __restrict__ out1) {
    const int b = blockIdx.x, tid = threadIdx.x;
    const int lane = tid & 63, wid = tid >> 6;
    __shared__ float hm[512];
    __shared__ float q[512];
    __shared__ float sc[16];
    __shared__ float red[4];
    for (int d0 = tid; d0 < 512; d0 += 256)
        hm[d0] = hsum[b * 512 + d0] * (1.f / 4096.f);
    __syncthreads();
    for (int n = tid; n < 512; n += 256) {
        float s = Wqb[n];
        for (int k = 0; k < 512; ++k) s += hm[k] * Wq[(size_t)k * 512 + n];
        q[n] = s;
    }
    float gp = 0.f;
    for (int k = tid; k < 512; k += 256) gp += hm[k] * gw[k];
#pragma unroll
    for (int o = 32; o; o >>= 1) gp += __shfl_down(gp, o);
    if (!lane) red[wid] = gp;
    __syncthreads();
    const float g = 1.f / (1.f + __expf(-(red[0] + red[1] + red[2] + red[3] + gb[0])));
    for (int kk = wid; kk < 16; kk += 4) {
        float sp = 0.f;
        const float* kr = keys + ((size_t)(b * 16 + kk)) * 512;
        for (int k2 = lane; k2 < 512; k2 += 64) sp += q[k2] * kr[k2];
#pragma unroll
        for (int o = 32; o; o >>= 1) sp += __shfl_down(sp, o);
        if (!lane) sc[kk] = sp * 0.04419417382415922f;
    }
    __syncthreads();
    float mx = sc[0];
#pragma unroll
    for (int kk = 1; kk < 16; ++kk) mx = fmaxf(mx, sc[kk]);
    float den = 0.f;
    float w16[16];
#pragma unroll
    for (int kk = 0; kk < 16; ++kk) { w16[kk] = __expf(sc[kk] - mx); den += w16[kk]; }
    const float rden = 1.f / den;
    for (int d0 = tid; d0 < 512; d0 += 256) {
        float co = 0.f;
#pragma unroll
        for (int kk = 0; kk < 16; ++kk)
            co += w16[kk] * vals[((size_t)(b * 16 + kk)) * 512 + d0];
        out1[b * 512 + d0] = hm[d0] + g * (co * rden);
    }
}

// ---------------------------------------------------------------- launch
extern "C" void kernel_launch(void* const* d_in, const int* in_sizes, int n_in,
                              void* d_out, int out_size, void* d_ws, size_t ws_size,
                              hipStream_t stream) {
    const float* x    = (const float*)d_in[0];
    const float* ln1g = (const float*)d_in[1];
    const float* ln1b = (const float*)d_in[2];
    const float* ln2g = (const float*)d_in[3];
    const float* ln2b = (const float*)d_in[4];
    const float* Wp_w = (const float*)d_in[5];
    const float* Wp_b = (const float*)d_in[6];
    const float* Wt_w = (const float*)d_in[7];
    const float* Wt_b = (const float*)d_in[8];
    const float* Wr_w = (const float*)d_in[9];
    const float* Wr_b = (const float*)d_in[10];
    const float* Wi_w = (const float*)d_in[11];
    const float* Wi_b = (const float*)d_in[12];
    const float* Wk_w = (const float*)d_in[13];
    const float* Wk_b = (const float*)d_in[14];
    const float* Wv_w = (const float*)d_in[15];
    const float* Wv_b = (const float*)d_in[16];
    const float* Wq_w = (const float*)d_in[17];
    const float* Wq_b = (const float*)d_in[18];
    const float* gw   = (const float*)d_in[19];
    const float* gb   = (const float*)d_in[20];
    const float* f1w  = (const float*)d_in[21];
    const float* f1b  = (const float*)d_in[22];
    const float* f2w  = (const float*)d_in[23];
    const float* f2b  = (const float*)d_in[24];

    char* wsp = (char*)d_ws;
    bf16* lint4 = (bf16*)wsp;                        // [M][512][4] bf16 (67MB)
    char* p = wsp + 67108864;
    bf16* h_re = (bf16*)p;   p += 16777216;          // [M][512] bf16
    bf16* xn = (bf16*)p;     p += 16777216;          // [M][512] bf16
    bf16* hn = (bf16*)p;     p += 16777216;          // [M][512] bf16
    bf16* wcat = (bf16*)p;   p += 2097152;           // [2048][512] bf16 (Bt)
    bf16* f1bt = (bf16*)p;   p += 2097152;           // [2048][512] bf16
    bf16* f2bt = (bf16*)p;   p += 2097152;           // [512][2048] bf16
    float* bcat = (float*)p; p += 8192;              // [2048]
    float* ps = (float*)p;   p += 65536;             // [B][T]
    float* pspart = (float*)p; p += 524288;          // [8][M]
    float* hsum = (float*)p; p += 8192;              // [B][512]
    int* tki = (int*)p;      p += 256;               // [B][16]
    float* keys = (float*)p; p += 131072;            // [B][16][512]
    float* valsb = (float*)p;                        // [B][16][512]
    bf16* act = (bf16*)wsp;                          // [M][2048] bf16 overlays lint4
    float* out0 = (float*)d_out;
    float* out1 = (float*)d_out + OUT1_OFF;

    dim3 tb(32, 8);
    transpose_bf16<<<dim3(16, 16), tb, 0, stream>>>(Wp_w, wcat + (size_t)0 * 512 * 512, 512, 512);
    transpose_bf16<<<dim3(16, 16), tb, 0, stream>>>(Wt_w, wcat + (size_t)1 * 512 * 512, 512, 512);
    transpose_bf16<<<dim3(16, 16), tb, 0, stream>>>(Wr_w, wcat + (size_t)2 * 512 * 512, 512, 512);
    transpose_bf16<<<dim3(16, 16), tb, 0, stream>>>(Wi_w, wcat + (size_t)3 * 512 * 512, 512, 512);
    transpose_bf16<<<dim3(64, 16), tb, 0, stream>>>(f1w, f1bt, 512, 2048);
    transpose_bf16<<<dim3(16, 64), tb, 0, stream>>>(f2w, f2bt, 2048, 512);
    pack_bias<<<8, 256, 0, stream>>>(Wp_b, Wt_b, Wr_b, Wi_b, bcat);

    // LN1 -> xn
    ln_kernel<<<4096, 256, 0, stream>>>(x, nullptr, ln1g, ln1b, xn);
    // fused 4-projection GEMM + transform epilogue -> lint4; pscalar partials
    gemm_bt<0><<<2048, 256, 0, stream>>>(xn, wcat, bcat, lint4, pspart, nullptr, nullptr, MM, 2048, 512);
    // p_scalar finalize
    pscalar_fin<<<64, 256, 0, stream>>>(pspart, ps);
    // zero hsum, then scan (ILP x2, h_mean fused, bf16 out)
    zero_kernel<<<8, 256, 0, stream>>>(hsum, 2048);
    scan_kernel<<<512, 256, 0, stream>>>(lint4, h_re, hsum);
    // cache path
    topk_kernel<<<4, 256, 0, stream>>>(ps, tki);
    kv_kernel<<<64, 256, 0, stream>>>(h_re, tki, Wk_w, Wk_b, Wv_w, Wv_b, keys, valsb);
    attn_out_kernel<<<4, 256, 0, stream>>>(hsum, Wq_w, Wq_b, gw, gb, keys, valsb, out1);
    // FFN path (act overlays lint4 -- safe: scan already consumed it)
    ln_kernel<<<4096, 256, 0, stream>>>(x, h_re, ln2g, ln2b, hn);
    gemm_bt<1><<<2048, 256, 0, stream>>>(hn, f1bt, f1b, act, nullptr, nullptr, nullptr, MM, 2048, 512);
    gemm_bt<2><<<512, 256, 0, stream>>>(act, f2bt, f2b, out0, nullptr, h_re, x, MM, 512, 2048);
}

// Round 15
// 389.856 us; speedup vs baseline: 1.1748x; 1.0384x over previous
//
#include <hip/hip_runtime.h>
#include <hip/hip_bf16.h>
#include <cstdint>
#include <cstddef>

typedef __bf16 bf16;
typedef __attribute__((ext_vector_type(8))) __bf16 bf16x8;
typedef __attribute__((ext_vector_type(4))) __bf16 bf16x4;
typedef __attribute__((ext_vector_type(4))) float f32x4;

#define BB 4
#define TT 4096
#define DD 512
#define MM (BB * TT)              // 16384 rows
#define OUT1_OFF ((size_t)MM * DD)

typedef __attribute__((address_space(1))) void as1_void;
typedef __attribute__((address_space(3))) void as3_void;

__device__ __forceinline__ void gl_lds16(const void* g, void* l) {
    __builtin_amdgcn_global_load_lds((as1_void*)(uintptr_t)g,
                                     (as3_void*)(uintptr_t)l, 16, 0, 0);
}

#define SIGM(x) (__builtin_amdgcn_rcpf(1.f + __expf(-(x))))

// ---------------------------------------------------------------- transpose
__global__ void transpose_bf16(const float* __restrict__ in, bf16* __restrict__ out,
                               int R, int C) {
    __shared__ float tile[32][33];
    const int c0 = blockIdx.x * 32, r0 = blockIdx.y * 32;
    const int tx = threadIdx.x, ty = threadIdx.y;
#pragma unroll
    for (int i = 0; i < 32; i += 8)
        tile[ty + i][tx] = in[(size_t)(r0 + ty + i) * C + (c0 + tx)];
    __syncthreads();
#pragma unroll
    for (int i = 0; i < 32; i += 8)
        out[(size_t)(c0 + ty + i) * R + (r0 + tx)] = (bf16)tile[tx][ty + i];
}

__global__ void pack_bias(const float* __restrict__ a, const float* __restrict__ b,
                          const float* __restrict__ c, const float* __restrict__ d,
                          float* __restrict__ o) {
    const int i = blockIdx.x * 256 + threadIdx.x;
    if (i < 2048) {
        const float* s = (i < 512) ? a : (i < 1024) ? b : (i < 1536) ? c : d;
        o[i] = s[i & 511];
    }
}

__global__ void zero_kernel(float* __restrict__ p, int n) {
    const int i = blockIdx.x * 256 + threadIdx.x;
    if (i < n) p[i] = 0.f;
}

// ---------------------------------------------------------------- layernorm 1
// xn = LN(x)*g+b (bf16); also emits xbf = (bf16)x for downstream readers.
__global__ __launch_bounds__(256) void ln1_kernel(
    const float* __restrict__ X, const float* __restrict__ gw,
    const float* __restrict__ bw, bf16* __restrict__ out,
    bf16* __restrict__ xbf) {
    const int row = blockIdx.x * 4 + (threadIdx.x >> 6);
    const int lane = threadIdx.x & 63;
    const float* xr = X + (size_t)row * DD + lane * 8;
    float v[8];
    float4 v0 = *(const float4*)xr;
    float4 v1 = *(const float4*)(xr + 4);
    v[0] = v0.x; v[1] = v0.y; v[2] = v0.z; v[3] = v0.w;
    v[4] = v1.x; v[5] = v1.y; v[6] = v1.z; v[7] = v1.w;
    bf16x8 c8;
#pragma unroll
    for (int i = 0; i < 8; ++i) c8[i] = (bf16)v[i];
    *(bf16x8*)(xbf + (size_t)row * DD + lane * 8) = c8;
    float s = 0.f, ss = 0.f;
#pragma unroll
    for (int i = 0; i < 8; ++i) { s += v[i]; ss += v[i] * v[i]; }
#pragma unroll
    for (int o = 32; o; o >>= 1) { s += __shfl_down(s, o); ss += __shfl_down(ss, o); }
    s = __shfl(s, 0); ss = __shfl(ss, 0);
    const float mu = s * (1.f / DD);
    const float var = ss * (1.f / DD) - mu * mu;
    const float rstd = rsqrtf(var + 1e-5f);
    bf16x8 o8;
#pragma unroll
    for (int i = 0; i < 8; ++i)
        o8[i] = (bf16)((v[i] - mu) * rstd * gw[lane * 8 + i] + bw[lane * 8 + i]);
    *(bf16x8*)(out + (size_t)row * DD + lane * 8) = o8;
}

// ---------------------------------------------------------------- layernorm 2
// hn = LN(xbf + h_re)*g+b  (both inputs bf16)
__global__ __launch_bounds__(256) void ln2_kernel(
    const bf16* __restrict__ Xb, const bf16* __restrict__ Xadd,
    const float* __restrict__ gw, const float* __restrict__ bw,
    bf16* __restrict__ out) {
    const int row = blockIdx.x * 4 + (threadIdx.x >> 6);
    const int lane = threadIdx.x & 63;
    const bf16x8 x8 = *(const bf16x8*)(Xb + (size_t)row * DD + lane * 8);
    const bf16x8 a8 = *(const bf16x8*)(Xadd + (size_t)row * DD + lane * 8);
    float v[8];
#pragma unroll
    for (int i = 0; i < 8; ++i) v[i] = (float)x8[i] + (float)a8[i];
    float s = 0.f, ss = 0.f;
#pragma unroll
    for (int i = 0; i < 8; ++i) { s += v[i]; ss += v[i] * v[i]; }
#pragma unroll
    for (int o = 32; o; o >>= 1) { s += __shfl_down(s, o); ss += __shfl_down(ss, o); }
    s = __shfl(s, 0); ss = __shfl(ss, 0);
    const float mu = s * (1.f / DD);
    const float var = ss * (1.f / DD) - mu * mu;
    const float rstd = rsqrtf(var + 1e-5f);
    bf16x8 o8;
#pragma unroll
    for (int i = 0; i < 8; ++i)
        o8[i] = (bf16)((v[i] - mu) * rstd * gw[lane * 8 + i] + bw[lane * 8 + i]);
    *(bf16x8*)(out + (size_t)row * DD + lane * 8) = o8;
}

#define MF(a_, b_, c_) c_ = __builtin_amdgcn_mfma_f32_16x16x32_bf16(a_, b_, c_, 0, 0, 0)

// ---------------------------------------------------------------- GEMM (bf16 MFMA)
// BM=256 x BN=128, BK=32, 8 waves (4M x 2N), per-wave tile 64x64 (acc 4x4 --
// IDENTICAL wave-level code to the proven R12 kernel). Tri-buffered
// counted-vmcnt, one barrier per K-step, T2 both-sides XOR swizzle.
// 72KB LDS => 2 blocks/CU (16 waves/CU). Halves block-K-steps per CU to
// amortize the measured ~1840cyc/step fixed overhead.
// MODE 0: fused transform epilogue (lint4 {om,th,re,im} + pscalar partials)
// MODE 1: bf16 out = gelu(acc + bias)
// MODE 2: f32 out = acc + bias + add1(bf16 h_re) + add2(bf16 x)
template <int MODE>
__global__ __launch_bounds__(512, 4) void gemm_bt(
    const bf16* __restrict__ A, const bf16* __restrict__ Bt,
    const float* __restrict__ bias, void* __restrict__ Cout,
    void* __restrict__ Cout2,
    const bf16* __restrict__ add1, const bf16* __restrict__ add2,
    int M, int N, int K) {
    __shared__ bf16 As[3][8192];    // 256 rows x 32
    __shared__ bf16 Bs[3][4096];    // 128 rows x 32
    const int tid = threadIdx.x;
    const int lane = tid & 63;
    const int wv = tid >> 6;            // 0..7
    const int wr = wv >> 1, wc = wv & 1;
    const int nb = N >> 7;
    const int nwg = gridDim.x;
    int bx = blockIdx.x;
    if ((nwg & 7) == 0) bx = (bx & 7) * (nwg >> 3) + (bx >> 3);  // XCD swizzle
    const int bm = bx / nb, bn = bx % nb;
    const int m0 = bm << 8, n0 = bn << 7;

    const int srow = tid >> 2;                              // staging row (0..127)
    const int scol = (((tid & 3) ^ ((tid >> 3) & 3)) << 3); // pre-swizzled global col
    const bf16* Asrc = A + (size_t)(m0 + srow) * K + scol;
    const bf16* Bsrc = Bt + (size_t)(n0 + srow) * K + scol;
    const size_t rstepA = (size_t)128 * K;

    const int lr = lane & 15, lg = lane >> 4;
    const int sel = ((lg ^ ((lr >> 1) & 3)) << 3);          // swizzled 16B slot
    const int aoff = (wr * 64 + lr) * 32 + sel;
    const int boff = (wc * 64 + lr) * 32 + sel;

#define STG(buf, k0)                                                 \
    do {                                                             \
        gl_lds16(Asrc + (k0),          &As[buf][wv * 512]);          \
        gl_lds16(Asrc + (k0) + rstepA, &As[buf][wv * 512 + 4096]);   \
        gl_lds16(Bsrc + (k0),          &Bs[buf][wv * 512]);          \
    } while (0)

    f32x4 acc00 = {}, acc01 = {}, acc02 = {}, acc03 = {};
    f32x4 acc10 = {}, acc11 = {}, acc12 = {}, acc13 = {};
    f32x4 acc20 = {}, acc21 = {}, acc22 = {}, acc23 = {};
    f32x4 acc30 = {}, acc31 = {}, acc32 = {}, acc33 = {};

    const int NT = K >> 5;
    STG(0, 0);
    STG(1, 32);
    int cur = 0;                 // buffer of tile t (t % 3)
    for (int t = 0; t < NT; ++t) {
        if (t + 1 < NT) asm volatile("s_waitcnt vmcnt(3)" ::: "memory");
        else            asm volatile("s_waitcnt vmcnt(0)" ::: "memory");
        __builtin_amdgcn_s_barrier();
        asm volatile("" ::: "memory");
        const bf16* Ab = As[cur];
        const bf16* Bb = Bs[cur];
        bf16x8 af0 = *(const bf16x8*)&Ab[aoff];
        bf16x8 af1 = *(const bf16x8*)&Ab[aoff + 512];
        bf16x8 af2 = *(const bf16x8*)&Ab[aoff + 1024];
        bf16x8 af3 = *(const bf16x8*)&Ab[aoff + 1536];
        bf16x8 bf0 = *(const bf16x8*)&Bb[boff];
        bf16x8 bf1 = *(const bf16x8*)&Bb[boff + 512];
        bf16x8 bf2 = *(const bf16x8*)&Bb[boff + 1024];
        bf16x8 bf3 = *(const bf16x8*)&Bb[boff + 1536];
        if (t + 2 < NT) {
            const int stg = (cur == 0) ? 2 : cur - 1;
            STG(stg, (t + 2) << 5);
        }
        MF(af0, bf0, acc00); MF(af0, bf1, acc01); MF(af0, bf2, acc02); MF(af0, bf3, acc03);
        MF(af1, bf0, acc10); MF(af1, bf1, acc11); MF(af1, bf2, acc12); MF(af1, bf3, acc13);
        MF(af2, bf0, acc20); MF(af2, bf1, acc21); MF(af2, bf2, acc22); MF(af2, bf3, acc23);
        MF(af3, bf0, acc30); MF(af3, bf1, acc31); MF(af3, bf2, acc32); MF(af3, bf3, acc33);
        cur = (cur == 2) ? 0 : cur + 1;
    }
#undef STG

    if constexpr (MODE == 0) {
        const int cls = n0 >> 9;                 // 0=p 1=theta 2=re 3=im
        if (cls == 0) {
            const int pidx = (n0 + wc * 64) >> 6;    // 0..7
#define EPI0(mi, A0, A1, A2, A3)                                              \
    do {                                                                      \
        const int gmb = m0 + wr * 64 + mi * 16 + 4 * lg;                      \
        const int dbase = n0 + wc * 64 + lr;                                  \
        const float b0_ = bias[dbase], b1_ = bias[dbase + 16],                \
                    b2_ = bias[dbase + 32], b3_ = bias[dbase + 48];           \
        _Pragma("unroll")                                                     \
        for (int i = 0; i < 4; ++i) {                                         \
            const int row = gmb + i;                                          \
            const float p0 = SIGM(A0[i] + b0_);                               \
            const float p1 = SIGM(A1[i] + b1_);                               \
            const float p2 = SIGM(A2[i] + b2_);                               \
            const float p3 = SIGM(A3[i] + b3_);                               \
            bf16* ob = (bf16*)Cout + (size_t)row * 2048;                      \
            ob[(size_t)dbase * 4]        = (bf16)(1.f - p0);                  \
            ob[(size_t)(dbase + 16) * 4] = (bf16)(1.f - p1);                  \
            ob[(size_t)(dbase + 32) * 4] = (bf16)(1.f - p2);                  \
            ob[(size_t)(dbase + 48) * 4] = (bf16)(1.f - p3);                  \
            float s_ = p0 + p1 + p2 + p3;                                     \
            s_ += __shfl_xor(s_, 1); s_ += __shfl_xor(s_, 2);                 \
            s_ += __shfl_xor(s_, 4); s_ += __shfl_xor(s_, 8);                 \
            if (lr == 0) ((float*)Cout2)[(size_t)pidx * MM + row] = s_;       \
        }                                                                     \
    } while (0)
            EPI0(0, acc00, acc01, acc02, acc03);
            EPI0(1, acc10, acc11, acc12, acc13);
            EPI0(2, acc20, acc21, acc22, acc23);
            EPI0(3, acc30, acc31, acc32, acc33);
#undef EPI0
        } else {
#define EPIS(mi, ni, ACC)                                                     \
    do {                                                                      \
        const int gmb = m0 + wr * 64 + mi * 16 + 4 * lg;                      \
        const int gn = n0 + wc * 64 + ni * 16 + lr;                           \
        const int dn = gn & 511;                                              \
        const float bia = bias[gn];                                           \
        _Pragma("unroll")                                                     \
        for (int i = 0; i < 4; ++i)                                           \
            ((bf16*)Cout)[((size_t)(gmb + i) * 512 + dn) * 4 + cls] =         \
                (bf16)(ACC[i] + bia);                                         \
    } while (0)
            EPIS(0, 0, acc00); EPIS(0, 1, acc01); EPIS(0, 2, acc02); EPIS(0, 3, acc03);
            EPIS(1, 0, acc10); EPIS(1, 1, acc11); EPIS(1, 2, acc12); EPIS(1, 3, acc13);
            EPIS(2, 0, acc20); EPIS(2, 1, acc21); EPIS(2, 2, acc22); EPIS(2, 3, acc23);
            EPIS(3, 0, acc30); EPIS(3, 1, acc31); EPIS(3, 2, acc32); EPIS(3, 3, acc33);
#undef EPIS
        }
    } else {
#define EPI(mi, ni, ACC)                                                        \
    do {                                                                        \
        const int gmb = m0 + wr * 64 + mi * 16 + 4 * lg;                        \
        const int gn = n0 + wc * 64 + ni * 16 + lr;                             \
        const float bia = bias[gn];                                             \
        _Pragma("unroll")                                                       \
        for (int i = 0; i < 4; ++i) {                                           \
            float v = ACC[i] + bia;                                             \
            const int row = gmb + i;                                            \
            if (MODE == 1) {                                                    \
                const float ge = 0.5f * v * (1.0f + erff(v * 0.70710678118654752f)); \
                ((bf16*)Cout)[(size_t)row * N + gn] = (bf16)ge;                 \
            } else {                                                            \
                const size_t off = (size_t)row * N + gn;                        \
                ((float*)Cout)[off] = v + (float)add1[off] + (float)add2[off];  \
            }                                                                   \
        }                                                                       \
    } while (0)
        EPI(0, 0, acc00); EPI(0, 1, acc01); EPI(0, 2, acc02); EPI(0, 3, acc03);
        EPI(1, 0, acc10); EPI(1, 1, acc11); EPI(1, 2, acc12); EPI(1, 3, acc13);
        EPI(2, 0, acc20); EPI(2, 1, acc21); EPI(2, 2, acc22); EPI(2, 3, acc23);
        EPI(3, 0, acc30); EPI(3, 1, acc31); EPI(3, 2, acc32); EPI(3, 3, acc33);
#undef EPI
    }
}

// ---------------------------------------------------------------- p_scalar finalize
__global__ __launch_bounds__(256) void pscalar_fin(const float* __restrict__ part,
                                                   float* __restrict__ ps) {
    const int i = blockIdx.x * 256 + threadIdx.x;   // 16384 rows
    float s = 0.f;
#pragma unroll
    for (int j = 0; j < 8; ++j) s += part[(size_t)j * MM + i];
    ps[i] = s * (1.f / 512.f);
}

// ---------------------------------------------------------------- scan (ILP x2)
// 13-stage pipeline DP; two independent pipelines per thread; bf16 h_re out;
// h_mean partials in f32 pre-conversion.
#define SCL 32
#define STAGE13(par, pai, pbr, pbi, car, cai, br_, bi_)                     \
    _Pragma("unroll")                                                       \
    for (int k = 0; k < 13; ++k) {                                          \
        const float tar = par[k], tai = pai[k], tbr = pbr[k], tbi = pbi[k]; \
        par[k] = car; pai[k] = cai; pbr[k] = br_; pbi[k] = bi_;             \
        const float nbr = car * tbr - cai * tbi + br_;                      \
        const float nbi = car * tbi + cai * tbr + bi_;                      \
        if (k < 12) {                                                       \
            const float nar = car * tar - cai * tai;                        \
            const float nai = car * tai + cai * tar;                        \
            car = nar; cai = nai;                                           \
        }                                                                   \
        br_ = nbr; bi_ = nbi;                                               \
    }

#define XF(tp, car, cai, br_, bi_)                                       \
    {                                                                    \
        const bf16x4 q_ = *(const bf16x4*)(tp);                          \
        (tp) += 2048;                                                    \
        const float om_ = (float)q_[0];                                  \
        const float th_ = (float)q_[1];                                  \
        br_ = (float)q_[2];                                              \
        bi_ = (float)q_[3];                                              \
        float fr_, sn_, cs_;                                             \
        const float rv_ = th_ * 0.15915494309189535f;                    \
        asm("v_fract_f32 %0, %1" : "=v"(fr_) : "v"(rv_));                \
        asm("v_sin_f32 %0, %1" : "=v"(sn_) : "v"(fr_));                  \
        asm("v_cos_f32 %0, %1" : "=v"(cs_) : "v"(fr_));                  \
        car = om_ * cs_; cai = om_ * sn_;                                \
    }

__global__ __launch_bounds__(256) void scan_kernel(const bf16* __restrict__ lint4,
                                                   bf16* __restrict__ h_re,
                                                   float* __restrict__ hsum) {
    const int blk = blockIdx.x;          // 512 blocks
    const int b = blk >> 7;
    const int rem = blk & 127;
    const int dh = rem & 1;
    const int tcp = rem >> 1;            // 0..63
    const int d = dh * 256 + threadIdx.x;
    const int t0a = tcp * 64;
    const int t0b = t0a + 32;

    float parA[13], paiA[13], pbrA[13], pbiA[13];
    float parB[13], paiB[13], pbrB[13], pbiB[13];
#pragma unroll
    for (int k = 0; k < 13; ++k) {
        parA[k] = 0.f; paiA[k] = 0.f; pbrA[k] = 0.f; pbiA[k] = 0.f;
        parB[k] = 0.f; paiB[k] = 0.f; pbrB[k] = 0.f; pbiB[k] = 0.f;
    }

    const int warmA = (tcp == 0) ? 0 : 13;
    const bf16* tpA = lint4 + ((size_t)(b * TT + t0a - warmA) * 512 + d) * 4;
    const bf16* tpB = lint4 + ((size_t)(b * TT + t0b - 13) * 512 + d) * 4;
    bf16* poutA = h_re + ((size_t)(b * TT + t0a)) * DD + d;
    bf16* poutB = h_re + ((size_t)(b * TT + t0b)) * DD + d;

    float carA, caiA, brA, biA, carB, caiB, brB, biB;
    for (int s = 0; s < 13; ++s) {
        if (tcp != 0) {           // wave-uniform
            XF(tpA, carA, caiA, brA, biA)
            STAGE13(parA, paiA, pbrA, pbiA, carA, caiA, brA, biA)
        }
        XF(tpB, carB, caiB, brB, biB)
        STAGE13(parB, paiB, pbrB, pbiB, carB, caiB, brB, biB)
    }

    float hacc = 0.f;
#pragma unroll 2
    for (int s = 0; s < SCL; ++s) {
        XF(tpA, carA, caiA, brA, biA)
        if (tcp == 0 && s == 0) {
#pragma unroll
            for (int k = 0; k < 13; ++k) { parA[k] = carA; paiA[k] = caiA; pbrA[k] = brA; pbiA[k] = biA; }
        } else {
            STAGE13(parA, paiA, pbrA, pbiA, carA, caiA, brA, biA)
        }
        poutA[(size_t)s * DD] = (bf16)brA;
        hacc += brA;
        XF(tpB, carB, caiB, brB, biB)
        STAGE13(parB, paiB, pbrB, pbiB, carB, caiB, brB, biB)
        poutB[(size_t)s * DD] = (bf16)brB;
        hacc += brB;
    }
    atomicAdd(&hsum[b * DD + d], hacc);
}
#undef XF
#undef STAGE13

// ---------------------------------------------------------------- top-16
__global__ __launch_bounds__(256) void topk_kernel(const float* __restrict__ ps,
                                                   int* __restrict__ idx_out) {
    __shared__ float vals[TT];
    __shared__ float rv[4];
    __shared__ int ri[4];
    const int b = blockIdx.x, tid = threadIdx.x;
    for (int i = tid; i < TT; i += 256) vals[i] = ps[b * TT + i];
    __syncthreads();
    for (int kk = 0; kk < 16; ++kk) {
        float bv = -1e30f; int bi = 0x7fffffff;
        for (int i = tid; i < TT; i += 256) {
            const float v = vals[i];
            if (v > bv || (v == bv && i < bi)) { bv = v; bi = i; }
        }
#pragma unroll
        for (int o = 32; o; o >>= 1) {
            const float ov = __shfl_down(bv, o);
            const int oi = __shfl_down(bi, o);
            if (ov > bv || (ov == bv && oi < bi)) { bv = ov; bi = oi; }
        }
        const int lane = tid & 63, wid = tid >> 6;
        if (!lane) { rv[wid] = bv; ri[wid] = bi; }
        __syncthreads();
        if (!tid) {
            float fbv = rv[0]; int fbi = ri[0];
            for (int w = 1; w < 4; ++w)
                if (rv[w] > fbv || (rv[w] == fbv && ri[w] < fbi)) { fbv = rv[w]; fbi = ri[w]; }
            idx_out[b * 16 + kk] = fbi;
            vals[fbi] = -1e30f;
        }
        __syncthreads();
    }
}

// ---------------------------------------------------------------- keys/values
__global__ __launch_bounds__(256) void kv_kernel(
    const bf16* __restrict__ h_re, const int* __restrict__ tki,
    const float* __restrict__ Wk, const float* __restrict__ Wkb,
    const float* __restrict__ Wv, const float* __restrict__ Wvb,
    float* __restrict__ keys, float* __restrict__ vals) {
    const int blk = blockIdx.x;
    const int b = blk >> 4, j = blk & 15;
    const int tid = threadIdx.x;
    __shared__ float hrow[512];
    const int row = tki[b * 16 + j];
    for (int i = tid; i < 512; i += 256)
        hrow[i] = (float)h_re[((size_t)(b * TT + row)) * DD + i];
    __syncthreads();
    for (int n = tid; n < 512; n += 256) {
        float sk = Wkb[n], sv = Wvb[n];
        for (int k = 0; k < 512; ++k) {
            const float h = hrow[k];
            sk += h * Wk[(size_t)k * 512 + n];
            sv += h * Wv[(size_t)k * 512 + n];
        }
        keys[((size_t)(b * 16 + j)) * 512 + n] = sk;
        vals[((size_t)(b * 16 + j)) * 512 + n] = sv;
    }
}

// ---------------------------------------------------------------- query/gate/attn/out
__global__ __launch_bounds__(256) void attn_out_kernel(
    const float* __restrict__ hsum, const float* __restrict__ Wq,
    const float* __restrict__ Wqb, const float* __restrict__ gw,
    const float* __restrict__ gb, const float* __restrict__ keys,
    const float* __restrict__ vals, float* __restrict__ out1) {
    const int b = blockIdx.x, tid = threadIdx.x;
    const int lane = tid & 63, wid = tid >> 6;
    __shared__ float hm[512];
    __shared__ float q[512];
    __shared__ float sc[16];
    __shared__ float red[4];
    for (int d0 = tid; d0 < 512; d0 += 256)
        hm[d0] = hsum[b * 512 + d0] * (1.f / 4096.f);
    __syncthreads();
    for (int n = tid; n < 512; n += 256) {
        float s = Wqb[n];
        for (int k = 0; k < 512; ++k) s += hm[k] * Wq[(size_t)k * 512 + n];
        q[n] = s;
    }
    float gp = 0.f;
    for (int k = tid; k < 512; k += 256) gp += hm[k] * gw[k];
#pragma unroll
    for (int o = 32; o; o >>= 1) gp += __shfl_down(gp, o);
    if (!lane) red[wid] = gp;
    __syncthreads();
    const float g = 1.f / (1.f + __expf(-(red[0] + red[1] + red[2] + red[3] + gb[0])));
    for (int kk = wid; kk < 16; kk += 4) {
        float sp = 0.f;
        const float* kr = keys + ((size_t)(b * 16 + kk)) * 512;
        for (int k2 = lane; k2 < 512; k2 += 64) sp += q[k2] * kr[k2];
#pragma unroll
        for (int o = 32; o; o >>= 1) sp += __shfl_down(sp, o);
        if (!lane) sc[kk] = sp * 0.04419417382415922f;
    }
    __syncthreads();
    float mx = sc[0];
#pragma unroll
    for (int kk = 1; kk < 16; ++kk) mx = fmaxf(mx, sc[kk]);
    float den = 0.f;
    float w16[16];
#pragma unroll
    for (int kk = 0; kk < 16; ++kk) { w16[kk] = __expf(sc[kk] - mx); den += w16[kk]; }
    const float rden = 1.f / den;
    for (int d0 = tid; d0 < 512; d0 += 256) {
        float co = 0.f;
#pragma unroll
        for (int kk = 0; kk < 16; ++kk)
            co += w16[kk] * vals[((size_t)(b * 16 + kk)) * 512 + d0];
        out1[b * 512 + d0] = hm[d0] + g * (co * rden);
    }
}

// ---------------------------------------------------------------- launch
extern "C" void kernel_launch(void* const* d_in, const int* in_sizes, int n_in,
                              void* d_out, int out_size, void* d_ws, size_t ws_size,
                              hipStream_t stream) {
    const float* x    = (const float*)d_in[0];
    const float* ln1g = (const float*)d_in[1];
    const float* ln1b = (const float*)d_in[2];
    const float* ln2g = (const float*)d_in[3];
    const float* ln2b = (const float*)d_in[4];
    const float* Wp_w = (const float*)d_in[5];
    const float* Wp_b = (const float*)d_in[6];
    const float* Wt_w = (const float*)d_in[7];
    const float* Wt_b = (const float*)d_in[8];
    const float* Wr_w = (const float*)d_in[9];
    const float* Wr_b = (const float*)d_in[10];
    const float* Wi_w = (const float*)d_in[11];
    const float* Wi_b = (const float*)d_in[12];
    const float* Wk_w = (const float*)d_in[13];
    const float* Wk_b = (const float*)d_in[14];
    const float* Wv_w = (const float*)d_in[15];
    const float* Wv_b = (const float*)d_in[16];
    const float* Wq_w = (const float*)d_in[17];
    const float* Wq_b = (const float*)d_in[18];
    const float* gw   = (const float*)d_in[19];
    const float* gb   = (const float*)d_in[20];
    const float* f1w  = (const float*)d_in[21];
    const float* f1b  = (const float*)d_in[22];
    const float* f2w  = (const float*)d_in[23];
    const float* f2b  = (const float*)d_in[24];

    char* wsp = (char*)d_ws;
    bf16* lint4 = (bf16*)wsp;                        // [M][512][4] bf16 (67MB)
    char* p = wsp + 67108864;
    bf16* h_re = (bf16*)p;   p += 16777216;          // [M][512] bf16
    bf16* xn = (bf16*)p;     p += 16777216;          // [M][512] bf16
    bf16* hn = (bf16*)p;     p += 16777216;          // [M][512] bf16
    bf16* xbf = (bf16*)p;    p += 16777216;          // [M][512] bf16 (x copy)
    bf16* wcat = (bf16*)p;   p += 2097152;           // [2048][512] bf16 (Bt)
    bf16* f1bt = (bf16*)p;   p += 2097152;           // [2048][512] bf16
    bf16* f2bt = (bf16*)p;   p += 2097152;           // [512][2048] bf16
    float* bcat = (float*)p; p += 8192;              // [2048]
    float* ps = (float*)p;   p += 65536;             // [B][T]
    float* pspart = (float*)p; p += 524288;          // [8][M]
    float* hsum = (float*)p; p += 8192;              // [B][512]
    int* tki = (int*)p;      p += 256;               // [B][16]
    float* keys = (float*)p; p += 131072;            // [B][16][512]
    float* valsb = (float*)p;                        // [B][16][512]
    bf16* act = (bf16*)wsp;                          // [M][2048] bf16 overlays lint4
    float* out0 = (float*)d_out;
    float* out1 = (float*)d_out + OUT1_OFF;

    dim3 tb(32, 8);
    transpose_bf16<<<dim3(16, 16), tb, 0, stream>>>(Wp_w, wcat + (size_t)0 * 512 * 512, 512, 512);
    transpose_bf16<<<dim3(16, 16), tb, 0, stream>>>(Wt_w, wcat + (size_t)1 * 512 * 512, 512, 512);
    transpose_bf16<<<dim3(16, 16), tb, 0, stream>>>(Wr_w, wcat + (size_t)2 * 512 * 512, 512, 512);
    transpose_bf16<<<dim3(16, 16), tb, 0, stream>>>(Wi_w, wcat + (size_t)3 * 512 * 512, 512, 512);
    transpose_bf16<<<dim3(64, 16), tb, 0, stream>>>(f1w, f1bt, 512, 2048);
    transpose_bf16<<<dim3(16, 64), tb, 0, stream>>>(f2w, f2bt, 2048, 512);
    pack_bias<<<8, 256, 0, stream>>>(Wp_b, Wt_b, Wr_b, Wi_b, bcat);

    // LN1 -> xn (+ bf16 x copy)
    ln1_kernel<<<4096, 256, 0, stream>>>(x, ln1g, ln1b, xn, xbf);
    // fused 4-projection GEMM (256x128 8-wave tri) -> lint4; pscalar partials
    gemm_bt<0><<<1024, 512, 0, stream>>>(xn, wcat, bcat, lint4, pspart, nullptr, nullptr, MM, 2048, 512);
    // p_scalar finalize
    pscalar_fin<<<64, 256, 0, stream>>>(pspart, ps);
    // zero hsum, then scan (ILP x2, h_mean fused, bf16 out)
    zero_kernel<<<8, 256, 0, stream>>>(hsum, 2048);
    scan_kernel<<<512, 256, 0, stream>>>(lint4, h_re, hsum);
    // cache path
    topk_kernel<<<4, 256, 0, stream>>>(ps, tki);
    kv_kernel<<<64, 256, 0, stream>>>(h_re, tki, Wk_w, Wk_b, Wv_w, Wv_b, keys, valsb);
    attn_out_kernel<<<4, 256, 0, stream>>>(hsum, Wq_w, Wq_b, gw, gb, keys, valsb, out1);
    // FFN path (act overlays lint4 -- safe: scan already consumed it)
    ln2_kernel<<<4096, 256, 0, stream>>>(xbf, h_re, ln2g, ln2b, hn);
    gemm_bt<1><<<1024, 512, 0, stream>>>(hn, f1bt, f1b, act, nullptr, nullptr, nullptr, MM, 2048, 512);
    gemm_bt<2><<<256, 512, 0, stream>>>(act, f2bt, f2b, out0, nullptr, h_re, xbf, MM, 512, 2048);
}